// Round 1
// baseline (1276.226 us; speedup 1.0000x reference)
//
#include <hip/hip_runtime.h>

#define CH 64

// ---------------- degree count (float atomics; counts < 2^24 so exact) ------
__global__ void deg_kernel(const int* __restrict__ src, const int* __restrict__ dst,
                           float* __restrict__ outdeg, float* __restrict__ indeg, int E)
{
    int stride = gridDim.x * blockDim.x;
    for (int e = blockIdx.x * blockDim.x + threadIdx.x; e < E; e += stride) {
        atomicAdd(&outdeg[src[e]], 1.0f);
        atomicAdd(&indeg[dst[e]], 1.0f);
    }
}

// ---------------- deg -> norm in place --------------------------------------
__global__ void norm_kernel(float* __restrict__ a, float* __restrict__ b, int N)
{
    int i = blockIdx.x * blockDim.x + threadIdx.x;
    if (i < N) {
        float d = a[i];
        a[i] = (d > 0.0f) ? rsqrtf(d) : 0.0f;
        float e = b[i];
        b[i] = (e > 0.0f) ? rsqrtf(e) : 0.0f;
    }
}

// ---------------- h = (x * norm_src) @ W  (row per thread, W scalarized) ----
__global__ __launch_bounds__(256) void gemm_kernel(const float* __restrict__ x,
                                                   const float* __restrict__ norm_src,
                                                   const float* __restrict__ W,
                                                   float* __restrict__ h, int N)
{
    int row = blockIdx.x * blockDim.x + threadIdx.x;
    if (row >= N) return;
    float ns = norm_src[row];
    float xr[CH];
    const float4* xp = (const float4*)(x + (size_t)row * CH);
    #pragma unroll
    for (int j = 0; j < CH / 4; ++j) {
        float4 v = xp[j];
        xr[4 * j + 0] = v.x * ns;
        xr[4 * j + 1] = v.y * ns;
        xr[4 * j + 2] = v.z * ns;
        xr[4 * j + 3] = v.w * ns;
    }
    float* hp = h + (size_t)row * CH;
    for (int c0 = 0; c0 < CH; c0 += 16) {
        float acc[16];
        #pragma unroll
        for (int q = 0; q < 16; ++q) acc[q] = 0.0f;
        #pragma unroll 8
        for (int k = 0; k < CH; ++k) {
            const float xk = xr[k];
            #pragma unroll
            for (int q = 0; q < 4; ++q) {
                // address is wave-uniform -> compiler emits s_load (W is 16 KB)
                float4 w = *(const float4*)(W + k * CH + c0 + q * 4);
                acc[q * 4 + 0] += xk * w.x;
                acc[q * 4 + 1] += xk * w.y;
                acc[q * 4 + 2] += xk * w.z;
                acc[q * 4 + 3] += xk * w.w;
            }
        }
        #pragma unroll
        for (int q = 0; q < 4; ++q) {
            float4 o;
            o.x = acc[q * 4 + 0];
            o.y = acc[q * 4 + 1];
            o.z = acc[q * 4 + 2];
            o.w = acc[q * 4 + 3];
            *(float4*)(hp + c0 + q * 4) = o;
        }
    }
}

// ---------------- scatter-add: out[dst] += h[src] ---------------------------
// thread = (edge, 4-channel chunk): float4 gather + 4 atomicAdds
__global__ void scatter_kernel(const float* __restrict__ h,
                               const int* __restrict__ src, const int* __restrict__ dst,
                               float* __restrict__ out, int E)
{
    long long total = (long long)E * 16;
    long long stride = (long long)gridDim.x * blockDim.x;
    for (long long g = blockIdx.x * (long long)blockDim.x + threadIdx.x; g < total; g += stride) {
        int e   = (int)(g >> 4);
        int sub = (int)(g & 15);
        int s = src[e];
        int d = dst[e];
        float4 v = *(const float4*)(h + (size_t)s * CH + sub * 4);
        float* o = out + (size_t)d * CH + sub * 4;
        atomicAdd(o + 0, v.x);
        atomicAdd(o + 1, v.y);
        atomicAdd(o + 2, v.z);
        atomicAdd(o + 3, v.w);
    }
}

// ---------------- out = out * norm_dst + b (in place) -----------------------
__global__ void scale_kernel(float* __restrict__ out, const float* __restrict__ norm_dst,
                             const float* __restrict__ bias, int N)
{
    int g = blockIdx.x * blockDim.x + threadIdx.x;
    int total = N * 16;
    if (g >= total) return;
    int node = g >> 4;
    int c4   = (g & 15) * 4;
    float nd = norm_dst[node];
    float4 v = *(float4*)(out + (size_t)node * CH + c4);
    const float4 b = *(const float4*)(bias + c4);
    v.x = v.x * nd + b.x;
    v.y = v.y * nd + b.y;
    v.z = v.z * nd + b.z;
    v.w = v.w * nd + b.w;
    *(float4*)(out + (size_t)node * CH + c4) = v;
}

extern "C" void kernel_launch(void* const* d_in, const int* in_sizes, int n_in,
                              void* d_out, int out_size, void* d_ws, size_t ws_size,
                              hipStream_t stream)
{
    const float* x    = (const float*)d_in[0];
    const int*   edge = (const int*)d_in[1];
    const float* W    = (const float*)d_in[2];
    const float* bias = (const float*)d_in[3];
    float* out = (float*)d_out;

    int N = in_sizes[0] / CH;   // 100000
    int E = in_sizes[1] / 2;    // 1280000
    const int* src = edge;
    const int* dst = edge + E;

    // workspace layout: [norm_src N][norm_dst N][pad to 256][h N*CH]
    char* ws = (char*)d_ws;
    float* norm_src = (float*)ws;
    float* norm_dst = norm_src + N;
    size_t hoff = ((size_t)2 * N * sizeof(float) + 255) & ~(size_t)255;
    float* h = (float*)(ws + hoff);

    hipMemsetAsync(norm_src, 0, (size_t)2 * N * sizeof(float), stream);
    hipMemsetAsync(out, 0, (size_t)N * CH * sizeof(float), stream);

    deg_kernel<<<2048, 256, 0, stream>>>(src, dst, norm_src, norm_dst, E);
    norm_kernel<<<(N + 255) / 256, 256, 0, stream>>>(norm_src, norm_dst, N);
    gemm_kernel<<<(N + 255) / 256, 256, 0, stream>>>(x, norm_src, W, h, N);
    scatter_kernel<<<4096, 256, 0, stream>>>(h, src, dst, out, E);
    scale_kernel<<<((N * 16) + 255) / 256, 256, 0, stream>>>(out, norm_dst, bias, N);
}

// Round 2
// 451.465 us; speedup vs baseline: 2.8269x; 2.8269x over previous
//
#include <hip/hip_runtime.h>

#define CH 64

// ---------------- degree histogram (int atomics) ----------------------------
__global__ void count_kernel(const int* __restrict__ src, const int* __restrict__ dst,
                             int* __restrict__ outdeg, int* __restrict__ indeg, int E)
{
    int e = blockIdx.x * blockDim.x + threadIdx.x;
    if (e < E) {
        atomicAdd(&outdeg[src[e]], 1);
        atomicAdd(&indeg[dst[e]], 1);
    }
}

// ---------------- exclusive scan of indeg -> row_ptr (single block) ---------
__global__ __launch_bounds__(256) void scan_kernel(const int* __restrict__ indeg,
                                                   int* __restrict__ row_ptr, int N)
{
    __shared__ int sums[256];
    int tid = threadIdx.x;
    int C = (N + 255) / 256;
    int start = tid * C;
    int end = min(start + C, N);
    int s = 0;
    for (int i = start; i < end; ++i) s += indeg[i];
    sums[tid] = s;
    __syncthreads();
    // Hillis-Steele inclusive scan
    for (int d = 1; d < 256; d <<= 1) {
        int v = (tid >= d) ? sums[tid - d] : 0;
        __syncthreads();
        sums[tid] += v;
        __syncthreads();
    }
    int running = (tid > 0) ? sums[tid - 1] : 0;  // exclusive offset
    for (int i = start; i < end; ++i) {
        row_ptr[i] = running;
        running += indeg[i];
    }
    if (tid == 255) row_ptr[N] = running;  // thread 255 always covers the tail
}

// ---------------- h = (x * norm_src) @ W  (row per thread, W scalarized) ----
__global__ __launch_bounds__(256) void gemm_kernel(const float* __restrict__ x,
                                                   const int* __restrict__ outdeg,
                                                   const float* __restrict__ W,
                                                   float* __restrict__ h, int N)
{
    int row = blockIdx.x * blockDim.x + threadIdx.x;
    if (row >= N) return;
    int od = outdeg[row];
    float ns = (od > 0) ? rsqrtf((float)od) : 0.0f;
    float xr[CH];
    const float4* xp = (const float4*)(x + (size_t)row * CH);
    #pragma unroll
    for (int j = 0; j < CH / 4; ++j) {
        float4 v = xp[j];
        xr[4 * j + 0] = v.x * ns;
        xr[4 * j + 1] = v.y * ns;
        xr[4 * j + 2] = v.z * ns;
        xr[4 * j + 3] = v.w * ns;
    }
    float* hp = h + (size_t)row * CH;
    for (int c0 = 0; c0 < CH; c0 += 16) {
        float acc[16];
        #pragma unroll
        for (int q = 0; q < 16; ++q) acc[q] = 0.0f;
        #pragma unroll 8
        for (int k = 0; k < CH; ++k) {
            const float xk = xr[k];
            #pragma unroll
            for (int q = 0; q < 4; ++q) {
                float4 w = *(const float4*)(W + k * CH + c0 + q * 4);  // wave-uniform -> s_load
                acc[q * 4 + 0] += xk * w.x;
                acc[q * 4 + 1] += xk * w.y;
                acc[q * 4 + 2] += xk * w.z;
                acc[q * 4 + 3] += xk * w.w;
            }
        }
        #pragma unroll
        for (int q = 0; q < 4; ++q) {
            float4 o;
            o.x = acc[q * 4 + 0];
            o.y = acc[q * 4 + 1];
            o.z = acc[q * 4 + 2];
            o.w = acc[q * 4 + 3];
            *(float4*)(hp + c0 + q * 4) = o;
        }
    }
}

// ---------------- CSR fill: csr_src[row_ptr[dst]+k] = src --------------------
__global__ void fill_kernel(const int* __restrict__ src, const int* __restrict__ dst,
                            const int* __restrict__ row_ptr, int* __restrict__ fill_cnt,
                            int* __restrict__ csr_src, int E)
{
    int e = blockIdx.x * blockDim.x + threadIdx.x;
    if (e < E) {
        int d = dst[e];
        int pos = row_ptr[d] + atomicAdd(&fill_cnt[d], 1);
        csr_src[pos] = src[e];
    }
}

// ---------------- aggregate: wave per node, lane = channel -------------------
// out[n][lane] = (sum_{e in N(n)} h[src_e][lane]) * norm_dst(n) + bias[lane]
__global__ __launch_bounds__(256) void agg_kernel(const float* __restrict__ h,
                                                  const int* __restrict__ csr_src,
                                                  const int* __restrict__ row_ptr,
                                                  const float* __restrict__ bias,
                                                  float* __restrict__ out, int N)
{
    int wave = (blockIdx.x * blockDim.x + threadIdx.x) >> 6;
    int lane = threadIdx.x & 63;
    if (wave >= N) return;
    int beg = row_ptr[wave];
    int endp = row_ptr[wave + 1];
    float a0 = 0.0f, a1 = 0.0f, a2 = 0.0f, a3 = 0.0f;
    int e = beg;
    for (; e + 4 <= endp; e += 4) {
        int s0 = csr_src[e + 0];
        int s1 = csr_src[e + 1];
        int s2 = csr_src[e + 2];
        int s3 = csr_src[e + 3];
        a0 += h[(size_t)s0 * CH + lane];
        a1 += h[(size_t)s1 * CH + lane];
        a2 += h[(size_t)s2 * CH + lane];
        a3 += h[(size_t)s3 * CH + lane];
    }
    for (; e < endp; ++e) a0 += h[(size_t)csr_src[e] * CH + lane];
    float acc = (a0 + a1) + (a2 + a3);
    int deg = endp - beg;
    float nd = (deg > 0) ? rsqrtf((float)deg) : 0.0f;
    out[(size_t)wave * CH + lane] = acc * nd + bias[lane];
}

extern "C" void kernel_launch(void* const* d_in, const int* in_sizes, int n_in,
                              void* d_out, int out_size, void* d_ws, size_t ws_size,
                              hipStream_t stream)
{
    const float* x    = (const float*)d_in[0];
    const int*   edge = (const int*)d_in[1];
    const float* W    = (const float*)d_in[2];
    const float* bias = (const float*)d_in[3];
    float* out = (float*)d_out;

    int N = in_sizes[0] / CH;   // 100000
    int E = in_sizes[1] / 2;    // 1280000
    const int* src = edge;
    const int* dst = edge + E;

    // workspace layout (ints are 4B):
    // [outdeg N][indeg N][fill_cnt N][row_ptr N+1][csr_src E][pad][h N*CH floats]
    int* base = (int*)d_ws;
    int* outdeg   = base;
    int* indeg    = base + N;
    int* fill_cnt = base + 2 * N;
    int* row_ptr  = base + 3 * N;
    int* csr_src  = base + 4 * N + 64;   // 64-int pad past row_ptr[N]
    size_t hoff = (((size_t)(4 * N + 64 + E) * sizeof(int)) + 255) & ~(size_t)255;
    float* h = (float*)((char*)d_ws + hoff);

    // zero the three count arrays (contiguous)
    hipMemsetAsync(base, 0, (size_t)3 * N * sizeof(int), stream);

    int eb = (E + 255) / 256;
    count_kernel<<<eb, 256, 0, stream>>>(src, dst, outdeg, indeg, E);
    scan_kernel<<<1, 256, 0, stream>>>(indeg, row_ptr, N);
    gemm_kernel<<<(N + 255) / 256, 256, 0, stream>>>(x, outdeg, W, h, N);
    fill_kernel<<<eb, 256, 0, stream>>>(src, dst, row_ptr, fill_cnt, csr_src, E);
    agg_kernel<<<((size_t)N * 64 + 255) / 256, 256, 0, stream>>>(h, csr_src, row_ptr, bias, out, N);
}

// Round 3
// 295.406 us; speedup vs baseline: 4.3202x; 1.5283x over previous
//
#include <hip/hip_runtime.h>

#define CH 64
#define SCAN_CHUNK 1024   // 256 threads x 4 elements

// ---------------- degree histogram (int atomics) ----------------------------
__global__ void count_kernel(const int* __restrict__ src, const int* __restrict__ dst,
                             int* __restrict__ outdeg, int* __restrict__ indeg, int E)
{
    int e = blockIdx.x * blockDim.x + threadIdx.x;
    if (e < E) {
        atomicAdd(&outdeg[src[e]], 1);
        atomicAdd(&indeg[dst[e]], 1);
    }
}

// ---------------- scan stage 1: per-block partial sums ----------------------
__global__ __launch_bounds__(256) void scan_partial_kernel(const int* __restrict__ indeg,
                                                           int* __restrict__ partial, int N)
{
    int tid = threadIdx.x;
    int base = blockIdx.x * SCAN_CHUNK + tid * 4;
    int s = 0;
    if (base + 3 < N) {
        int4 v = *(const int4*)(indeg + base);
        s = v.x + v.y + v.z + v.w;
    } else {
        for (int i = base; i < N && i < base + 4; ++i) s += indeg[i];
    }
    __shared__ int sm[256];
    sm[tid] = s;
    __syncthreads();
    for (int d = 128; d > 0; d >>= 1) {
        if (tid < d) sm[tid] += sm[tid + d];
        __syncthreads();
    }
    if (tid == 0) partial[blockIdx.x] = sm[0];
}

// ---------------- scan stage 2: exclusive scan of partials (NB <= 256) ------
__global__ __launch_bounds__(256) void scan_offsets_kernel(int* __restrict__ partial, int NB)
{
    __shared__ int sm[256];
    int tid = threadIdx.x;
    sm[tid] = (tid < NB) ? partial[tid] : 0;
    __syncthreads();
    for (int d = 1; d < 256; d <<= 1) {
        int v = (tid >= d) ? sm[tid - d] : 0;
        __syncthreads();
        sm[tid] += v;
        __syncthreads();
    }
    if (tid < NB) partial[tid] = (tid > 0) ? sm[tid - 1] : 0;
}

// ---------------- scan stage 3: block-local scan + global offset ------------
__global__ __launch_bounds__(256) void scan_write_kernel(const int* __restrict__ indeg,
                                                         const int* __restrict__ partial,
                                                         int* __restrict__ row_ptr, int N, int E)
{
    int tid = threadIdx.x;
    int base = blockIdx.x * SCAN_CHUNK + tid * 4;
    int v0 = 0, v1 = 0, v2 = 0, v3 = 0;
    if (base + 3 < N) {
        int4 v = *(const int4*)(indeg + base);
        v0 = v.x; v1 = v.y; v2 = v.z; v3 = v.w;
    } else {
        if (base + 0 < N) v0 = indeg[base + 0];
        if (base + 1 < N) v1 = indeg[base + 1];
        if (base + 2 < N) v2 = indeg[base + 2];
        if (base + 3 < N) v3 = indeg[base + 3];
    }
    __shared__ int sm[256];
    sm[tid] = v0 + v1 + v2 + v3;
    __syncthreads();
    for (int d = 1; d < 256; d <<= 1) {
        int t = (tid >= d) ? sm[tid - d] : 0;
        __syncthreads();
        sm[tid] += t;
        __syncthreads();
    }
    int off = partial[blockIdx.x] + ((tid > 0) ? sm[tid - 1] : 0);
    if (base + 0 < N) row_ptr[base + 0] = off;
    if (base + 1 < N) row_ptr[base + 1] = off + v0;
    if (base + 2 < N) row_ptr[base + 2] = off + v0 + v1;
    if (base + 3 < N) row_ptr[base + 3] = off + v0 + v1 + v2;
    if (blockIdx.x == 0 && tid == 0) row_ptr[N] = E;  // total is statically known
}

// ---------------- h = (x * norm_src) @ W  (row per thread, W scalarized) ----
__global__ __launch_bounds__(256) void gemm_kernel(const float* __restrict__ x,
                                                   const int* __restrict__ outdeg,
                                                   const float* __restrict__ W,
                                                   float* __restrict__ h, int N)
{
    int row = blockIdx.x * blockDim.x + threadIdx.x;
    if (row >= N) return;
    int od = outdeg[row];
    float ns = (od > 0) ? rsqrtf((float)od) : 0.0f;
    float xr[CH];
    const float4* xp = (const float4*)(x + (size_t)row * CH);
    #pragma unroll
    for (int j = 0; j < CH / 4; ++j) {
        float4 v = xp[j];
        xr[4 * j + 0] = v.x * ns;
        xr[4 * j + 1] = v.y * ns;
        xr[4 * j + 2] = v.z * ns;
        xr[4 * j + 3] = v.w * ns;
    }
    float* hp = h + (size_t)row * CH;
    for (int c0 = 0; c0 < CH; c0 += 16) {
        float acc[16];
        #pragma unroll
        for (int q = 0; q < 16; ++q) acc[q] = 0.0f;
        #pragma unroll 8
        for (int k = 0; k < CH; ++k) {
            const float xk = xr[k];
            #pragma unroll
            for (int q = 0; q < 4; ++q) {
                float4 w = *(const float4*)(W + k * CH + c0 + q * 4);  // wave-uniform -> s_load
                acc[q * 4 + 0] += xk * w.x;
                acc[q * 4 + 1] += xk * w.y;
                acc[q * 4 + 2] += xk * w.z;
                acc[q * 4 + 3] += xk * w.w;
            }
        }
        #pragma unroll
        for (int q = 0; q < 4; ++q) {
            float4 o;
            o.x = acc[q * 4 + 0];
            o.y = acc[q * 4 + 1];
            o.z = acc[q * 4 + 2];
            o.w = acc[q * 4 + 3];
            *(float4*)(hp + c0 + q * 4) = o;
        }
    }
}

// ---------------- CSR fill: csr_src[row_ptr[dst]+k] = src --------------------
__global__ void fill_kernel(const int* __restrict__ src, const int* __restrict__ dst,
                            const int* __restrict__ row_ptr, int* __restrict__ fill_cnt,
                            int* __restrict__ csr_src, int E)
{
    int e = blockIdx.x * blockDim.x + threadIdx.x;
    if (e < E) {
        int d = dst[e];
        int pos = row_ptr[d] + atomicAdd(&fill_cnt[d], 1);
        csr_src[pos] = src[e];
    }
}

// ---------------- aggregate: wave per node, lane = channel -------------------
__global__ __launch_bounds__(256) void agg_kernel(const float* __restrict__ h,
                                                  const int* __restrict__ csr_src,
                                                  const int* __restrict__ row_ptr,
                                                  const float* __restrict__ bias,
                                                  float* __restrict__ out, int N)
{
    int wave = (blockIdx.x * blockDim.x + threadIdx.x) >> 6;
    int lane = threadIdx.x & 63;
    if (wave >= N) return;
    int beg = row_ptr[wave];
    int endp = row_ptr[wave + 1];
    float a0 = 0.0f, a1 = 0.0f, a2 = 0.0f, a3 = 0.0f;
    int e = beg;
    for (; e + 4 <= endp; e += 4) {
        int s0 = csr_src[e + 0];
        int s1 = csr_src[e + 1];
        int s2 = csr_src[e + 2];
        int s3 = csr_src[e + 3];
        a0 += h[(size_t)s0 * CH + lane];
        a1 += h[(size_t)s1 * CH + lane];
        a2 += h[(size_t)s2 * CH + lane];
        a3 += h[(size_t)s3 * CH + lane];
    }
    for (; e < endp; ++e) a0 += h[(size_t)csr_src[e] * CH + lane];
    float acc = (a0 + a1) + (a2 + a3);
    int deg = endp - beg;
    float nd = (deg > 0) ? rsqrtf((float)deg) : 0.0f;
    out[(size_t)wave * CH + lane] = acc * nd + bias[lane];
}

extern "C" void kernel_launch(void* const* d_in, const int* in_sizes, int n_in,
                              void* d_out, int out_size, void* d_ws, size_t ws_size,
                              hipStream_t stream)
{
    const float* x    = (const float*)d_in[0];
    const int*   edge = (const int*)d_in[1];
    const float* W    = (const float*)d_in[2];
    const float* bias = (const float*)d_in[3];
    float* out = (float*)d_out;

    int N = in_sizes[0] / CH;   // 100000
    int E = in_sizes[1] / 2;    // 1280000
    const int* src = edge;
    const int* dst = edge + E;

    // workspace layout (ints are 4B):
    // [outdeg N][indeg N][fill_cnt N][row_ptr N+1][pad][partial 256][csr_src E][pad][h N*CH]
    int* base = (int*)d_ws;
    int* outdeg   = base;
    int* indeg    = base + N;
    int* fill_cnt = base + 2 * N;
    int* row_ptr  = base + 3 * N;
    int* partial  = base + 4 * N + 64;
    int* csr_src  = base + 4 * N + 64 + 256;
    size_t hoff = (((size_t)(4 * N + 64 + 256 + E) * sizeof(int)) + 255) & ~(size_t)255;
    float* h = (float*)((char*)d_ws + hoff);

    hipMemsetAsync(base, 0, (size_t)3 * N * sizeof(int), stream);

    int eb = (E + 255) / 256;
    int NB = (N + SCAN_CHUNK - 1) / SCAN_CHUNK;  // 98 <= 256
    count_kernel<<<eb, 256, 0, stream>>>(src, dst, outdeg, indeg, E);
    scan_partial_kernel<<<NB, 256, 0, stream>>>(indeg, partial, N);
    scan_offsets_kernel<<<1, 256, 0, stream>>>(partial, NB);
    scan_write_kernel<<<NB, 256, 0, stream>>>(indeg, partial, row_ptr, N, E);
    gemm_kernel<<<(N + 255) / 256, 256, 0, stream>>>(x, outdeg, W, h, N);
    fill_kernel<<<eb, 256, 0, stream>>>(src, dst, row_ptr, fill_cnt, csr_src, E);
    agg_kernel<<<((size_t)N * 64 + 255) / 256, 256, 0, stream>>>(h, csr_src, row_ptr, bias, out, N);
}